// Round 1
// baseline (217.502 us; speedup 1.0000x reference)
//
#include <hip/hip_runtime.h>
#include <cstdint>

typedef __attribute__((ext_vector_type(8))) short short8;
typedef __attribute__((ext_vector_type(4))) short short4v;
typedef __attribute__((ext_vector_type(4))) float f32x4;
typedef __attribute__((ext_vector_type(4))) uint32_t uint4v;

#define EPSV 1e-5f

// geometry
#define IMG   3136        // 56*56
#define NPIX  100352      // 32*3136
#define PADIMG 430592     // 58*58*128
#define PADTOT 13778944   // 32*PADIMG

static __device__ __forceinline__ short f2bf(float f) {
  uint32_t u = __float_as_uint(f);
  u = (u + 0x7FFFu + ((u >> 16) & 1u)) >> 16;   // RNE, no NaN in this data
  return (short)u;
}

// ---------------- zero pads ----------------
__global__ void k_zero(uint4v* p, long n16) {
  long i = (long)blockIdx.x * blockDim.x + threadIdx.x;
  long stride = (long)gridDim.x * blockDim.x;
  uint4v z = {0u, 0u, 0u, 0u};
  for (; i < n16; i += stride) p[i] = z;
}

// ---------------- weight fake-quant: store integer levels (exact in bf16) + scale ----------------
__global__ void k_wquant(const float* __restrict__ w1, const float* __restrict__ w2,
                         short* __restrict__ wj1, short* __restrict__ wj2,
                         float* __restrict__ ws1, float* __restrict__ ws2) {
  int o = blockIdx.x & 127;
  bool second = blockIdx.x >= 128;
  const float* src = (second ? w2 : w1) + o * 1152;
  short* wj = second ? wj2 : wj1;
  float* wsc = second ? ws2 : ws1;
  __shared__ float red[256];
  int t = threadIdx.x;
  float m = 0.f;
  for (int i = t; i < 1152; i += 256) m = fmaxf(m, fabsf(src[i]));
  red[t] = m;
  __syncthreads();
  for (int s = 128; s > 0; s >>= 1) {
    if (t < s) red[t] = fmaxf(red[t], red[t + s]);
    __syncthreads();
  }
  float s = fmaxf(red[0] / 127.0f, 1e-8f);
  if (t == 0) wsc[o] = s;
  for (int i = t; i < 1152; i += 256) {
    float q = rintf(src[i] / s);              // round then clip, like reference
    q = fminf(fmaxf(q, -127.f), 127.f);
    int ci = i / 9, tap = i - ci * 9;         // w[o][ci][kh][kw] -> tap-major [tap][o][ci]
    wj[(tap * 128 + o) * 128 + ci] = f2bf(q); // integer level, exact in bf16
  }
}

// ---------------- fold BN/PACT params ----------------
__global__ void k_params(const float* g1, const float* b1, const float* m1, const float* v1, const float* a1,
                         const float* g2, const float* b2, const float* m2, const float* v2, const float* a2,
                         const float* a3, const float* ws1, const float* ws2,
                         f32x4* pp1, f32x4* pp2, f32x4* pp3) {
  int c = threadIdx.x;
  if (c < 128) {
    float r1 = 1.0f / sqrtf(v1[c] + EPSV);
    float sc1 = g1[c] * r1;
    pp1[c] = (f32x4){ws1[c] * sc1, b1[c] - m1[c] * sc1, 255.0f / a1[c], a1[c] / 255.0f};
    float r2 = 1.0f / sqrtf(v2[c] + EPSV);
    float sc2 = g2[c] * r2;
    pp2[c] = (f32x4){ws2[c] * sc2, b2[c] - m2[c] * sc2, 255.0f / a2[c], a2[c] / 255.0f};
    pp3[c] = (f32x4){a3[c] / 255.0f, 255.0f / a3[c], a3[c], 0.0f};
  }
}

// ---------------- NCHW fp32 -> padded NHWC bf16 (hi+lo split) ----------------
__global__ void k_transform(const float* __restrict__ x, short* __restrict__ xph, short* __restrict__ xpl) {
  int b = blockIdx.x;           // 0..1791 = n*56+h
  int n = b / 56, h = b - (b / 56) * 56;
  __shared__ float lds[7168];   // [128ci][56w]
  const float* base = x + (size_t)n * 401408 + h * 56;
  int t = threadIdx.x;
  for (int idx = t; idx < 7168; idx += 256) {
    int ci = idx / 56, w = idx - ci * 56;
    lds[idx] = base[ci * 3136 + w];
  }
  __syncthreads();
  int ob = ((n * 58 + h + 1) * 58 + 1) * 128;
  for (int idx = t; idx < 7168; idx += 256) {
    int w = idx >> 7, ci = idx & 127;
    float v = lds[ci * 56 + w];
    short hb = f2bf(v);
    float hf = __uint_as_float(((uint32_t)(uint16_t)hb) << 16);
    short lb = f2bf(v - hf);
    xph[ob + w * 128 + ci] = hb;
    xpl[ob + w * 128 + ci] = lb;
  }
}

// ---------------- conv1: A = int weight levels, B = {x_hi, x_lo}; BN+PACT epilogue -> bf16 NHWC ----------------
__global__ __launch_bounds__(256) void k_conv1(
    const short* __restrict__ xph, const short* __restrict__ xpl,
    const short* __restrict__ wj1, const f32x4* __restrict__ pp1,
    short* __restrict__ o1p) {
  __shared__ short smem[18432];
  short* Al = smem;
  short* Bl = smem + 9216;
  const int t = threadIdx.x;
  const int l = t & 63;
  const int wv = t >> 6;
  const int wr = wv >> 1, wc = wv & 1;
  const int lane15 = l & 15, hi4 = l >> 4;
  const int px0 = blockIdx.x * 128;
  const int srow = t >> 3, seg = t & 7;

  int pixbase[4];
#pragma unroll
  for (int r = 0; r < 4; ++r) {
    unsigned gpx = px0 + r * 32 + srow;
    unsigned n = gpx / IMG;
    unsigned rem = gpx - n * IMG;
    unsigned h = rem / 56;
    unsigned w = rem - h * 56;
    pixbase[r] = (int)(((n * 58u + h) * 58u + w) * 128u) + seg * 8;
  }

  f32x4 acc[4][4];
#pragma unroll
  for (int i = 0; i < 4; ++i)
#pragma unroll
    for (int j = 0; j < 4; ++j) acc[i][j] = (f32x4){0.f, 0.f, 0.f, 0.f};

#pragma unroll 1
  for (int tap = 0; tap < 9; ++tap) {
    const int tapoff = ((tap / 3) * 58 + (tap - (tap / 3) * 3)) * 128;
#pragma unroll 1
    for (int ch = 0; ch < 4; ++ch) {
      const short* xsrc = (ch < 2) ? xph : xpl;
      const int cioff = (ch & 1) * 64;
      uint4v av[4], bv[4];
#pragma unroll
      for (int r = 0; r < 4; ++r) {
        int row = r * 32 + srow;
        av[r] = *(const uint4v*)(wj1 + ((tap * 128 + row) * 128 + cioff + seg * 8));
        bv[r] = *(const uint4v*)(xsrc + (pixbase[r] + tapoff + cioff));
      }
#pragma unroll
      for (int r = 0; r < 4; ++r) {
        int row = r * 32 + srow;
        *(uint4v*)&Al[row * 72 + seg * 8] = av[r];   // rows padded to 144B: b128 reads at conflict minimum
        *(uint4v*)&Bl[row * 72 + seg * 8] = bv[r];
      }
      __syncthreads();
#pragma unroll
      for (int kk = 0; kk < 2; ++kk) {
        short8 a[4], b[4];
#pragma unroll
        for (int m = 0; m < 4; ++m)
          a[m] = *(const short8*)&Al[(wr * 64 + m * 16 + lane15) * 72 + kk * 32 + hi4 * 8];
#pragma unroll
        for (int n2 = 0; n2 < 4; ++n2)
          b[n2] = *(const short8*)&Bl[(wc * 64 + n2 * 16 + lane15) * 72 + kk * 32 + hi4 * 8];
#pragma unroll
        for (int m = 0; m < 4; ++m)
#pragma unroll
          for (int n2 = 0; n2 < 4; ++n2)
            acc[m][n2] = __builtin_amdgcn_mfma_f32_16x16x32_bf16(a[m], b[n2], acc[m][n2], 0, 0, 0);
      }
      __syncthreads();
    }
  }

  // epilogue: BN + PACT, pack bf16, LDS transpose to [px][co] for coalesced NHWC store
#pragma unroll
  for (int m = 0; m < 4; ++m) {
    const int cobase = wr * 64 + m * 16 + 4 * hi4;
#pragma unroll
    for (int n2 = 0; n2 < 4; ++n2) {
      const int pxl = wc * 64 + n2 * 16 + lane15;
      short4v ov;
#pragma unroll
      for (int r = 0; r < 4; ++r) {
        f32x4 p = pp1[cobase + r];
        float y = acc[m][n2][r] * p[0] + p[1];
        float cv = fminf(fmaxf(y, 0.f), p[3] * 255.0f);
        float act = rintf(cv * p[2]) * p[3];
        ov[r] = f2bf(act);
      }
      *(short4v*)&smem[pxl * 136 + cobase] = ov;     // 272B rows: 16B-aligned b128 readback
    }
  }
  __syncthreads();
  {
    const int pxl = t >> 1, half = t & 1;
    unsigned gpx = px0 + pxl;
    unsigned n = gpx / IMG;
    unsigned rem = gpx - n * IMG;
    unsigned h = rem / 56;
    unsigned w = rem - h * 56;
    int ob = (int)(((n * 58u + h + 1u) * 58u + (w + 1u)) * 128u) + half * 64;
#pragma unroll
    for (int i = 0; i < 8; ++i) {
      uint4v v = *(uint4v*)&smem[pxl * 136 + half * 64 + i * 8];
      *(uint4v*)(o1p + ob + i * 8) = v;
    }
  }
}

// ---------------- conv2 + BN + PACT + requant residual + final PACT -> fp32 NCHW ----------------
__global__ __launch_bounds__(256) void k_conv2(
    const short* __restrict__ o1p, const short* __restrict__ wj2,
    const f32x4* __restrict__ pp2, const f32x4* __restrict__ pp3,
    const float* __restrict__ x, float* __restrict__ out) {
  __shared__ short smem[18432];
  short* Al = smem;
  short* Bl = smem + 9216;
  const int t = threadIdx.x;
  const int l = t & 63;
  const int wv = t >> 6;
  const int wr = wv >> 1, wc = wv & 1;
  const int lane15 = l & 15, hi4 = l >> 4;
  const int px0 = blockIdx.x * 128;
  const int srow = t >> 3, seg = t & 7;

  int pixbase[4];
#pragma unroll
  for (int r = 0; r < 4; ++r) {
    unsigned gpx = px0 + r * 32 + srow;
    unsigned n = gpx / IMG;
    unsigned rem = gpx - n * IMG;
    unsigned h = rem / 56;
    unsigned w = rem - h * 56;
    pixbase[r] = (int)(((n * 58u + h) * 58u + w) * 128u) + seg * 8;
  }

  f32x4 acc[4][4];
#pragma unroll
  for (int i = 0; i < 4; ++i)
#pragma unroll
    for (int j = 0; j < 4; ++j) acc[i][j] = (f32x4){0.f, 0.f, 0.f, 0.f};

#pragma unroll 1
  for (int tap = 0; tap < 9; ++tap) {
    const int tapoff = ((tap / 3) * 58 + (tap - (tap / 3) * 3)) * 128;
#pragma unroll 1
    for (int ch = 0; ch < 2; ++ch) {
      const int cioff = ch * 64;
      uint4v av[4], bv[4];
#pragma unroll
      for (int r = 0; r < 4; ++r) {
        int row = r * 32 + srow;
        av[r] = *(const uint4v*)(wj2 + ((tap * 128 + row) * 128 + cioff + seg * 8));
        bv[r] = *(const uint4v*)(o1p + (pixbase[r] + tapoff + cioff));
      }
#pragma unroll
      for (int r = 0; r < 4; ++r) {
        int row = r * 32 + srow;
        *(uint4v*)&Al[row * 72 + seg * 8] = av[r];
        *(uint4v*)&Bl[row * 72 + seg * 8] = bv[r];
      }
      __syncthreads();
#pragma unroll
      for (int kk = 0; kk < 2; ++kk) {
        short8 a[4], b[4];
#pragma unroll
        for (int m = 0; m < 4; ++m)
          a[m] = *(const short8*)&Al[(wr * 64 + m * 16 + lane15) * 72 + kk * 32 + hi4 * 8];
#pragma unroll
        for (int n2 = 0; n2 < 4; ++n2)
          b[n2] = *(const short8*)&Bl[(wc * 64 + n2 * 16 + lane15) * 72 + kk * 32 + hi4 * 8];
#pragma unroll
        for (int m = 0; m < 4; ++m)
#pragma unroll
          for (int n2 = 0; n2 < 4; ++n2)
            acc[m][n2] = __builtin_amdgcn_mfma_f32_16x16x32_bf16(a[m], b[n2], acc[m][n2], 0, 0, 0);
      }
      __syncthreads();
    }
  }

  // epilogue: BN2 + PACT2 + requant(out,s3) + requant(x,s3) + add + PACT(a3); direct NCHW fp32 stores
#pragma unroll
  for (int n2 = 0; n2 < 4; ++n2) {
    unsigned gpx = px0 + wc * 64 + n2 * 16 + lane15;
    unsigned n = gpx / IMG;
    unsigned rem = gpx - n * IMG;
    unsigned h = rem / 56;
    unsigned w = rem - h * 56;
    int base = (int)(n * 401408u + h * 56u + w);
#pragma unroll
    for (int m = 0; m < 4; ++m) {
      int cobase = wr * 64 + m * 16 + 4 * hi4;
#pragma unroll
      for (int r = 0; r < 4; ++r) {
        int co = cobase + r;
        f32x4 p2 = pp2[co];
        f32x4 p3 = pp3[co];
        int off = base + co * 3136;
        float y = acc[m][n2][r] * p2[0] + p2[1];
        float cv = fminf(fmaxf(y, 0.f), p2[3] * 255.0f);
        float act = rintf(cv * p2[2]) * p2[3];
        float ro = rintf(act * p3[1]) * p3[0];
        float rx = rintf(x[off] * p3[1]) * p3[0];
        float y3 = ro + rx;
        float c3 = fminf(fmaxf(y3, 0.f), p3[2]);
        out[off] = rintf(c3 * p3[1]) * p3[0];
      }
    }
  }
}

extern "C" void kernel_launch(void* const* d_in, const int* in_sizes, int n_in,
                              void* d_out, int out_size, void* d_ws, size_t ws_size,
                              hipStream_t stream) {
  (void)in_sizes; (void)n_in; (void)out_size; (void)ws_size;
  const float* x  = (const float*)d_in[0];
  const float* w1 = (const float*)d_in[1];
  const float* g1 = (const float*)d_in[2];
  const float* b1 = (const float*)d_in[3];
  const float* m1 = (const float*)d_in[4];
  const float* v1 = (const float*)d_in[5];
  const float* a1 = (const float*)d_in[6];
  const float* w2 = (const float*)d_in[7];
  const float* g2 = (const float*)d_in[8];
  const float* b2 = (const float*)d_in[9];
  const float* m2 = (const float*)d_in[10];
  const float* v2 = (const float*)d_in[11];
  const float* a2 = (const float*)d_in[12];
  const float* a3 = (const float*)d_in[13];

  char* ws = (char*)d_ws;
  short* xph = (short*)(ws);
  short* xpl = (short*)(ws + (size_t)PADTOT * 2);
  short* o1p = (short*)(ws + (size_t)PADTOT * 4);
  short* wj1 = (short*)(ws + (size_t)PADTOT * 6);
  short* wj2 = (short*)(ws + (size_t)PADTOT * 6 + 294912);
  float* ws1 = (float*)(ws + (size_t)PADTOT * 6 + 2 * 294912);
  float* ws2 = ws1 + 128;
  f32x4* pp1 = (f32x4*)(ws2 + 128);
  f32x4* pp2 = pp1 + 128;
  f32x4* pp3 = pp2 + 128;

  k_zero<<<2048, 256, 0, stream>>>((uint4v*)ws, (long)PADTOT * 6 / 16);
  k_wquant<<<256, 256, 0, stream>>>(w1, w2, wj1, wj2, ws1, ws2);
  k_params<<<1, 128, 0, stream>>>(g1, b1, m1, v1, a1, g2, b2, m2, v2, a2, a3, ws1, ws2, pp1, pp2, pp3);
  k_transform<<<1792, 256, 0, stream>>>(x, xph, xpl);
  k_conv1<<<784, 256, 0, stream>>>(xph, xpl, wj1, pp1, o1p);
  k_conv2<<<784, 256, 0, stream>>>(o1p, wj2, pp2, pp3, x, (float*)d_out);
}

// Round 2
// 148.537 us; speedup vs baseline: 1.4643x; 1.4643x over previous
//
#include <hip/hip_runtime.h>
#include <cstdint>

typedef __attribute__((ext_vector_type(8))) short short8;
typedef __attribute__((ext_vector_type(4))) short short4v;
typedef __attribute__((ext_vector_type(4))) float f32x4;
typedef __attribute__((ext_vector_type(4))) int int4v;
typedef __attribute__((ext_vector_type(4))) uint32_t uint4v;

#define EPSV 1e-5f

// geometry
#define IMG   3136        // 56*56
#define NPIX  100352      // 32*3136
#define PADTOT 13778944   // 32 * 58*58*128 bytes (one int8 padded buffer)
#define S1Q (8.0f/127.0f)
#define S2Q (8.0f/(127.0f*254.0f))

static __device__ __forceinline__ short f2bf(float f) {
  uint32_t u = __float_as_uint(f);
  u = (u + 0x7FFFu + ((u >> 16) & 1u)) >> 16;   // RNE, no NaN in this data
  return (short)u;
}

// ---------------- halo-only zeroing: xq1/xq2 (int8 NHWC padded) + o1p (bf16 NHWC padded) ----------------
__global__ void k_halo(char* __restrict__ xq1, char* __restrict__ xq2, char* __restrict__ o1p) {
  int i = blockIdx.x * 256 + threadIdx.x;       // 0..233471 exact
  char* buf; int n, cid, pxc;
  if (i < 116736) {
    int j = (i < 58368) ? i : i - 58368;
    buf = (i < 58368) ? xq1 : xq2;
    n = j / 1824; cid = j - n * 1824; pxc = 8;  // pixel = 128 B = 8 chunks
  } else {
    int j = i - 116736;
    buf = o1p;
    n = j / 3648; cid = j - n * 3648; pxc = 16; // pixel = 256 B = 16 chunks
  }
  const int rowc = 58 * pxc;
  int chunk;
  if (cid < rowc) chunk = cid;                               // h = 0 row
  else if (cid < 2 * rowc) chunk = 57 * rowc + (cid - rowc); // h = 57 row
  else {
    int e = cid - 2 * rowc;
    int per_h = 2 * pxc;
    int h = 1 + e / per_h;
    int r = e - (e / per_h) * per_h;
    int w = (r < pxc) ? 0 : 57;
    chunk = h * rowc + w * pxc + (r & (pxc - 1));
  }
  long addr = ((long)n * (pxc == 8 ? 26912 : 53824) + chunk) * 16;
  *(uint4v*)(buf + addr) = (uint4v){0u, 0u, 0u, 0u};
}

// ---------------- weight fake-quant: conv1 -> int8 levels, conv2 -> bf16 integer levels ----------------
__global__ void k_wquant(const float* __restrict__ w1, const float* __restrict__ w2,
                         int8_t* __restrict__ wj1, short* __restrict__ wj2,
                         float* __restrict__ ws1, float* __restrict__ ws2) {
  int o = blockIdx.x & 127;
  bool second = blockIdx.x >= 128;
  const float* src = (second ? w2 : w1) + o * 1152;
  __shared__ float red[256];
  int t = threadIdx.x;
  float m = 0.f;
  for (int i = t; i < 1152; i += 256) m = fmaxf(m, fabsf(src[i]));
  red[t] = m;
  __syncthreads();
  for (int s = 128; s > 0; s >>= 1) {
    if (t < s) red[t] = fmaxf(red[t], red[t + s]);
    __syncthreads();
  }
  float s = fmaxf(red[0] / 127.0f, 1e-8f);
  if (t == 0) { if (second) ws2[o] = s; else ws1[o] = s; }
  for (int i = t; i < 1152; i += 256) {
    float q = rintf(src[i] / s);
    q = fminf(fmaxf(q, -127.f), 127.f);
    int ci = i / 9, tap = i - ci * 9;          // [tap][o][ci]
    if (second) wj2[(tap * 128 + o) * 128 + ci] = f2bf(q);
    else        wj1[(tap * 128 + o) * 128 + ci] = (int8_t)(int)q;
  }
}

// ---------------- fold BN/PACT params ----------------
__global__ void k_params(const float* g1, const float* b1, const float* m1, const float* v1, const float* a1,
                         const float* g2, const float* b2, const float* m2, const float* v2, const float* a2,
                         const float* a3, const float* ws1, const float* ws2,
                         f32x4* pp1, f32x4* pp2, f32x4* pp3) {
  int c = threadIdx.x;
  if (c < 128) {
    float r1 = 1.0f / sqrtf(v1[c] + EPSV);
    float sc1 = g1[c] * r1;
    pp1[c] = (f32x4){ws1[c] * sc1, b1[c] - m1[c] * sc1, 255.0f / a1[c], a1[c] / 255.0f};
    float r2 = 1.0f / sqrtf(v2[c] + EPSV);
    float sc2 = g2[c] * r2;
    pp2[c] = (f32x4){ws2[c] * sc2, b2[c] - m2[c] * sc2, 255.0f / a2[c], a2[c] / 255.0f};
    pp3[c] = (f32x4){a3[c] / 255.0f, 255.0f / a3[c], a3[c], 0.0f};
  }
}

// ---------------- NCHW fp32 -> padded NHWC int8 two-term quant (j1 coarse, j2 residual) ----------------
__global__ void k_transform(const float* __restrict__ x, int8_t* __restrict__ xq1, int8_t* __restrict__ xq2) {
  int b = blockIdx.x;           // 0..1791 = n*56+h
  int n = b / 56, h = b - (b / 56) * 56;
  __shared__ float lds[7296];   // [128ci][57] (+1 pad breaks 224-word stride)
  const float* base = x + (size_t)n * 401408 + h * 56;
  int t = threadIdx.x;
  for (int idx = t; idx < 7168; idx += 256) {
    int ci = idx / 56, w = idx - (idx / 56) * 56;
    lds[ci * 57 + w] = base[ci * 3136 + w];
  }
  __syncthreads();
  const int ob = ((n * 58 + h + 1) * 58 + 1) * 128;   // byte offset of (h+1, w=1), ci=0
  for (int idx = t; idx < 1792; idx += 256) {
    int w = idx >> 5, c4 = (idx & 31) * 4;
    uint32_t p1 = 0, p2 = 0;
#pragma unroll
    for (int j = 0; j < 4; ++j) {
      float v = lds[(c4 + j) * 57 + w];
      float j1 = rintf(v * (127.0f / 8.0f));
      j1 = fminf(fmaxf(j1, -127.f), 127.f);
      float rr = v - j1 * S1Q;
      float j2 = rintf(rr * ((127.0f * 254.0f) / 8.0f));
      j2 = fminf(fmaxf(j2, -127.f), 127.f);
      p1 |= ((uint32_t)((int)j1 & 0xff)) << (8 * j);
      p2 |= ((uint32_t)((int)j2 & 0xff)) << (8 * j);
    }
    *(uint32_t*)(xq1 + ob + w * 128 + c4) = p1;
    *(uint32_t*)(xq2 + ob + w * 128 + c4) = p2;
  }
}

// ---------------- conv1: int8 MFMA, exact two-term x; BN+PACT epilogue -> bf16 NHWC ----------------
__global__ __launch_bounds__(256, 2) void k_conv1(
    const int8_t* __restrict__ xq1, const int8_t* __restrict__ xq2,
    const int8_t* __restrict__ wj1, const f32x4* __restrict__ pp1,
    short* __restrict__ o1p) {
  __shared__ char smem[49152];
  char* Al = smem;               // 128co x 128ci, linear rows, XOR-swizzled 16B slots
  char* Bh = smem + 16384;       // 128px x 128ci (j1)
  char* Bl = smem + 32768;       // 128px x 128ci (j2)
  const int t = threadIdx.x;
  const int l = t & 63;
  const int wv = t >> 6;
  const int wr = wv >> 1, wc = wv & 1;
  const int lane15 = l & 15, hi4 = l >> 4;
  const int px0 = blockIdx.x * 128;
  const int srow = t >> 3, sl = t & 7;

  int pixbase[4];
#pragma unroll
  for (int r = 0; r < 4; ++r) {
    unsigned gpx = px0 + srow + 32 * r;
    unsigned n = gpx / IMG;
    unsigned rem = gpx - n * IMG;
    unsigned h = rem / 56;
    unsigned w = rem - h * 56;
    pixbase[r] = (int)(((n * 58u + h) * 58u + w) * 128u) + sl * 16;
  }

  int4v acc1[4][4], acc2[4][4];
#pragma unroll
  for (int i = 0; i < 4; ++i)
#pragma unroll
    for (int j = 0; j < 4; ++j) { acc1[i][j] = (int4v){0,0,0,0}; acc2[i][j] = (int4v){0,0,0,0}; }

#pragma unroll 1
  for (int tap = 0; tap < 9; ++tap) {
    const int kh = tap / 3, kw = tap - kh * 3;
    const int tapoff = (kh * 58 + kw) * 128;
    int4v av[4], bhv[4], blv[4];
#pragma unroll
    for (int r = 0; r < 4; ++r) {
      const int row = srow + 32 * r;
      av[r]  = *(const int4v*)(wj1 + (tap * 128 + row) * 128 + sl * 16);
      bhv[r] = *(const int4v*)(xq1 + pixbase[r] + tapoff);
      blv[r] = *(const int4v*)(xq2 + pixbase[r] + tapoff);
    }
    __syncthreads();     // previous tap's LDS reads done
#pragma unroll
    for (int r = 0; r < 4; ++r) {
      const int row = srow + 32 * r;
      const int ss = row * 128 + ((sl ^ (row & 7)) * 16);
      *(int4v*)&Al[ss] = av[r];
      *(int4v*)&Bh[ss] = bhv[r];
      *(int4v*)&Bl[ss] = blv[r];
    }
    __syncthreads();
#pragma unroll
    for (int kk = 0; kk < 2; ++kk) {
      int4v a[4];
#pragma unroll
      for (int m = 0; m < 4; ++m) {
        const int row = wr * 64 + m * 16 + lane15;
        a[m] = *(const int4v*)&Al[row * 128 + (((kk * 4 + hi4) ^ (row & 7)) * 16)];
      }
      int4v bv[4];
#pragma unroll
      for (int n2 = 0; n2 < 4; ++n2) {
        const int row = wc * 64 + n2 * 16 + lane15;
        bv[n2] = *(const int4v*)&Bh[row * 128 + (((kk * 4 + hi4) ^ (row & 7)) * 16)];
      }
#pragma unroll
      for (int m = 0; m < 4; ++m)
#pragma unroll
        for (int n2 = 0; n2 < 4; ++n2)
          acc1[m][n2] = __builtin_amdgcn_mfma_i32_16x16x64_i8(a[m], bv[n2], acc1[m][n2], 0, 0, 0);
#pragma unroll
      for (int n2 = 0; n2 < 4; ++n2) {
        const int row = wc * 64 + n2 * 16 + lane15;
        bv[n2] = *(const int4v*)&Bl[row * 128 + (((kk * 4 + hi4) ^ (row & 7)) * 16)];
      }
#pragma unroll
      for (int m = 0; m < 4; ++m)
#pragma unroll
        for (int n2 = 0; n2 < 4; ++n2)
          acc2[m][n2] = __builtin_amdgcn_mfma_i32_16x16x64_i8(a[m], bv[n2], acc2[m][n2], 0, 0, 0);
    }
  }

  __syncthreads();   // MFMA LDS reads done before epilogue reuses smem
  short* sT = (short*)smem;
  // epilogue: combine scales, BN + PACT, pack bf16, LDS transpose to [px][co]
#pragma unroll
  for (int m = 0; m < 4; ++m) {
    const int cobase = wr * 64 + m * 16 + 4 * hi4;
#pragma unroll
    for (int n2 = 0; n2 < 4; ++n2) {
      const int pxl = wc * 64 + n2 * 16 + lane15;
      short4v ov;
#pragma unroll
      for (int r = 0; r < 4; ++r) {
        f32x4 p = pp1[cobase + r];
        float accf = (float)acc1[m][n2][r] * S1Q + (float)acc2[m][n2][r] * S2Q;
        float y = accf * p[0] + p[1];
        float cv = fminf(fmaxf(y, 0.f), p[3] * 255.0f);
        float act = rintf(cv * p[2]) * p[3];
        ov[r] = f2bf(act);
      }
      *(short4v*)&sT[pxl * 136 + cobase] = ov;   // 272B rows, 16B-aligned readback
    }
  }
  __syncthreads();
  {
    const int pxl = t >> 1, half = t & 1;
    unsigned gpx = px0 + pxl;
    unsigned n = gpx / IMG;
    unsigned rem = gpx - n * IMG;
    unsigned h = rem / 56;
    unsigned w = rem - h * 56;
    int ob = (int)(((n * 58u + h + 1u) * 58u + (w + 1u)) * 128u) + half * 64;
#pragma unroll
    for (int i = 0; i < 8; ++i) {
      uint4v v = *(uint4v*)&sT[pxl * 136 + half * 64 + i * 8];
      *(uint4v*)(o1p + ob + i * 8) = v;
    }
  }
}

// ---------------- conv2 + BN + PACT + requant residual + final PACT -> fp32 NCHW (unchanged) ----------------
__global__ __launch_bounds__(256) void k_conv2(
    const short* __restrict__ o1p, const short* __restrict__ wj2,
    const f32x4* __restrict__ pp2, const f32x4* __restrict__ pp3,
    const float* __restrict__ x, float* __restrict__ out) {
  __shared__ short smem[18432];
  short* Al = smem;
  short* Bl = smem + 9216;
  const int t = threadIdx.x;
  const int l = t & 63;
  const int wv = t >> 6;
  const int wr = wv >> 1, wc = wv & 1;
  const int lane15 = l & 15, hi4 = l >> 4;
  const int px0 = blockIdx.x * 128;
  const int srow = t >> 3, seg = t & 7;

  int pixbase[4];
#pragma unroll
  for (int r = 0; r < 4; ++r) {
    unsigned gpx = px0 + r * 32 + srow;
    unsigned n = gpx / IMG;
    unsigned rem = gpx - n * IMG;
    unsigned h = rem / 56;
    unsigned w = rem - h * 56;
    pixbase[r] = (int)(((n * 58u + h) * 58u + w) * 128u) + seg * 8;
  }

  f32x4 acc[4][4];
#pragma unroll
  for (int i = 0; i < 4; ++i)
#pragma unroll
    for (int j = 0; j < 4; ++j) acc[i][j] = (f32x4){0.f, 0.f, 0.f, 0.f};

#pragma unroll 1
  for (int tap = 0; tap < 9; ++tap) {
    const int tapoff = ((tap / 3) * 58 + (tap - (tap / 3) * 3)) * 128;
#pragma unroll 1
    for (int ch = 0; ch < 2; ++ch) {
      const int cioff = ch * 64;
      uint4v av[4], bv[4];
#pragma unroll
      for (int r = 0; r < 4; ++r) {
        int row = r * 32 + srow;
        av[r] = *(const uint4v*)(wj2 + ((tap * 128 + row) * 128 + cioff + seg * 8));
        bv[r] = *(const uint4v*)(o1p + (pixbase[r] + tapoff + cioff));
      }
#pragma unroll
      for (int r = 0; r < 4; ++r) {
        int row = r * 32 + srow;
        *(uint4v*)&Al[row * 72 + seg * 8] = av[r];
        *(uint4v*)&Bl[row * 72 + seg * 8] = bv[r];
      }
      __syncthreads();
#pragma unroll
      for (int kk = 0; kk < 2; ++kk) {
        short8 a[4], b[4];
#pragma unroll
        for (int m = 0; m < 4; ++m)
          a[m] = *(const short8*)&Al[(wr * 64 + m * 16 + lane15) * 72 + kk * 32 + hi4 * 8];
#pragma unroll
        for (int n2 = 0; n2 < 4; ++n2)
          b[n2] = *(const short8*)&Bl[(wc * 64 + n2 * 16 + lane15) * 72 + kk * 32 + hi4 * 8];
#pragma unroll
        for (int m = 0; m < 4; ++m)
#pragma unroll
          for (int n2 = 0; n2 < 4; ++n2)
            acc[m][n2] = __builtin_amdgcn_mfma_f32_16x16x32_bf16(a[m], b[n2], acc[m][n2], 0, 0, 0);
      }
      __syncthreads();
    }
  }

#pragma unroll
  for (int n2 = 0; n2 < 4; ++n2) {
    unsigned gpx = px0 + wc * 64 + n2 * 16 + lane15;
    unsigned n = gpx / IMG;
    unsigned rem = gpx - n * IMG;
    unsigned h = rem / 56;
    unsigned w = rem - h * 56;
    int base = (int)(n * 401408u + h * 56u + w);
#pragma unroll
    for (int m = 0; m < 4; ++m) {
      int cobase = wr * 64 + m * 16 + 4 * hi4;
#pragma unroll
      for (int r = 0; r < 4; ++r) {
        int co = cobase + r;
        f32x4 p2 = pp2[co];
        f32x4 p3 = pp3[co];
        int off = base + co * 3136;
        float y = acc[m][n2][r] * p2[0] + p2[1];
        float cv = fminf(fmaxf(y, 0.f), p2[3] * 255.0f);
        float act = rintf(cv * p2[2]) * p2[3];
        float ro = rintf(act * p3[1]) * p3[0];
        float rx = rintf(x[off] * p3[1]) * p3[0];
        float y3 = ro + rx;
        float c3 = fminf(fmaxf(y3, 0.f), p3[2]);
        out[off] = rintf(c3 * p3[1]) * p3[0];
      }
    }
  }
}

extern "C" void kernel_launch(void* const* d_in, const int* in_sizes, int n_in,
                              void* d_out, int out_size, void* d_ws, size_t ws_size,
                              hipStream_t stream) {
  (void)in_sizes; (void)n_in; (void)out_size; (void)ws_size;
  const float* x  = (const float*)d_in[0];
  const float* w1 = (const float*)d_in[1];
  const float* g1 = (const float*)d_in[2];
  const float* b1 = (const float*)d_in[3];
  const float* m1 = (const float*)d_in[4];
  const float* v1 = (const float*)d_in[5];
  const float* a1 = (const float*)d_in[6];
  const float* w2 = (const float*)d_in[7];
  const float* g2 = (const float*)d_in[8];
  const float* b2 = (const float*)d_in[9];
  const float* m2 = (const float*)d_in[10];
  const float* v2 = (const float*)d_in[11];
  const float* a2 = (const float*)d_in[12];
  const float* a3 = (const float*)d_in[13];

  char* ws = (char*)d_ws;
  int8_t* xq1 = (int8_t*)ws;
  int8_t* xq2 = (int8_t*)(ws + (size_t)PADTOT);
  short*  o1p = (short*)(ws + 2 * (size_t)PADTOT);
  int8_t* wj1 = (int8_t*)(ws + 4 * (size_t)PADTOT);
  short*  wj2 = (short*)(ws + 4 * (size_t)PADTOT + 147456);
  float*  ws1 = (float*)(ws + 4 * (size_t)PADTOT + 147456 + 294912);
  float*  ws2 = ws1 + 128;
  f32x4*  pp1 = (f32x4*)(ws2 + 128);
  f32x4*  pp2 = pp1 + 128;
  f32x4*  pp3 = pp2 + 128;

  k_halo<<<912, 256, 0, stream>>>((char*)xq1, (char*)xq2, (char*)o1p);
  k_wquant<<<256, 256, 0, stream>>>(w1, w2, wj1, wj2, ws1, ws2);
  k_params<<<1, 128, 0, stream>>>(g1, b1, m1, v1, a1, g2, b2, m2, v2, a2, a3, ws1, ws2, pp1, pp2, pp3);
  k_transform<<<1792, 256, 0, stream>>>(x, xq1, xq2);
  k_conv1<<<784, 256, 0, stream>>>(xq1, xq2, wj1, pp1, o1p);
  k_conv2<<<784, 256, 0, stream>>>(o1p, wj2, pp2, pp3, x, (float*)d_out);
}